// Round 17
// baseline (301.210 us; speedup 1.0000x reference)
//
#include <hip/hip_runtime.h>
#include <hip/hip_fp16.h>
#include <math.h>

// ---------------------------------------------------------------------------
// Multi-layer diffractive optical model (4 layers, 48 images of 512x512 c64).
//   field = x*exp(i*phase*coeff); 4x [prop(H1); phase]; prop(H1*Hf); |field|^2
// FFT: 512-pt radix-8 Stockham, 3 stages, 64 lanes/transform, 8 elems/lane.
// Row pass: barrier-free (wave-private 4KB LDS, lgkmcnt fences) — at HBM peak.
// Col pass (k_col16): 1024 thr, 16 cols, ONE col/thread, 64KB SIDX16 stage.
//   r16 PMC: clean traffic (WRITE 52MB, FETCH 50MB, 0 conflicts) but
//   occupancy 34% = ONE resident block. History: VGPR 32/48 -> 78-79% (two
//   blocks); VGPR 52 -> 34% (one). => 48-VGPR boundary gates 2-block
//   residency for 1024-thr blocks (52 rounds to 64; 2x1024x64 = exactly
//   regsPerBlock). THIS ROUND: drop the h[8] prefetch (load H after the
//   forward FFT, consume immediately) to cut ~16 live VGPRs -> target <=48.
// FIELD fp16 interleaved between passes; all math fp32; H tables f32.
// ---------------------------------------------------------------------------

#define TWOPI_F 6.2831854820251465f
#define RSQ2    0.70710678f
#define NPIX    (48*512*512)

__device__ __forceinline__ float2 cadd(float2 a, float2 b){ return make_float2(a.x+b.x, a.y+b.y); }
__device__ __forceinline__ float2 csub(float2 a, float2 b){ return make_float2(a.x-b.x, a.y-b.y); }
__device__ __forceinline__ float2 cmul(float2 a, float2 b){ return make_float2(a.x*b.x - a.y*b.y, a.x*b.y + a.y*b.x); }

template<int S> __device__ __forceinline__ float2 mul_i(float2 a){   // * (S*i)
  return (S>0) ? make_float2(-a.y, a.x) : make_float2(a.y, -a.x);
}
template<int S> __device__ __forceinline__ float2 mul_w1(float2 a){  // * (1 + S*i)/sqrt2
  return (S>0) ? make_float2(RSQ2*(a.x-a.y), RSQ2*(a.x+a.y))
               : make_float2(RSQ2*(a.x+a.y), RSQ2*(a.y-a.x));
}
template<int S> __device__ __forceinline__ float2 mul_w3(float2 a){  // * (-1 + S*i)/sqrt2
  return (S>0) ? make_float2(RSQ2*(-a.x-a.y), RSQ2*(a.x-a.y))
               : make_float2(RSQ2*(a.y-a.x), RSQ2*(-a.x-a.y));
}
// tw stored with FORWARD sign (exp(-i theta)); S=+1 uses conjugate.
template<int S> __device__ __forceinline__ float2 cmul_tw(float2 v, float2 w){
  float wy = (S>0) ? -w.y : w.y;
  return make_float2(v.x*w.x - v.y*wy, v.x*wy + v.y*w.x);
}

// 8-point DIF DFT; outputs bit-reversed: A_k = d[km[k]], km = {0,4,2,6,1,5,3,7}
template<int S>
__device__ __forceinline__ void dft8(const float2* a, float2* d){
  float2 b0=cadd(a[0],a[4]), b1=cadd(a[1],a[5]), b2=cadd(a[2],a[6]), b3=cadd(a[3],a[7]);
  float2 b4=csub(a[0],a[4]);
  float2 b5=mul_w1<S>(csub(a[1],a[5]));
  float2 b6=mul_i<S> (csub(a[2],a[6]));
  float2 b7=mul_w3<S>(csub(a[3],a[7]));
  float2 c0=cadd(b0,b2), c2=csub(b0,b2);
  float2 c1=cadd(b1,b3), c3=mul_i<S>(csub(b1,b3));
  float2 c4=cadd(b4,b6), c6=csub(b4,b6);
  float2 c5=cadd(b5,b7), c7=mul_i<S>(csub(b5,b7));
  d[0]=cadd(c0,c1); d[1]=csub(c0,c1);
  d[2]=cadd(c2,c3); d[3]=csub(c2,c3);
  d[4]=cadd(c4,c5); d[5]=csub(c4,c5);
  d[6]=cadd(c6,c7); d[7]=csub(c6,c7);
}

// LDS swizzle for stride-1 wave-private buffers: b64 4-lane/bank-pair floor.
__device__ __forceinline__ int SWZR(int i){ return i ^ ((i>>4)&7); }
// 16-col stage swizzle: bank-pair = (cx+e)&15 -> 4 lanes/pair for all patterns.
__device__ __forceinline__ int SIDX16(int e, int cx){ return (e<<4) | ((cx + e) & 15); }

// Intra-wave LDS fence.
__device__ __forceinline__ void lds_fence(){ asm volatile("s_waitcnt lgkmcnt(0)" ::: "memory"); }

// Per-thread twiddles (forward sign), computed once per kernel.
__device__ __forceinline__ void make_tw(int t, float2* tw0, float2* tw1){
  float sn, cs;
  __sincosf((TWOPI_F/512.0f)*(float)t, &sn, &cs);
  float2 w0 = make_float2(cs, -sn);
  tw0[0] = make_float2(1.0f, 0.0f);
  #pragma unroll
  for(int k=1;k<8;k++) tw0[k] = cmul(tw0[k-1], w0);
  int p = t>>3;
  __sincosf((TWOPI_F/64.0f)*(float)p, &sn, &cs);
  float2 w1 = make_float2(cs, -sn);
  tw1[0] = make_float2(1.0f, 0.0f);
  #pragma unroll
  for(int k=1;k<8;k++) tw1[k] = cmul(tw1[k-1], w1);
}

// 512-pt FFT, wave-private single buffer, stride-1 + SWZR, NO block barriers.
template<int S>
__device__ __forceinline__ void fft512_wv(float2* a, float2* o, float2* B, int t,
                                          float scale, const float2* tw0, const float2* tw1){
  const int km[8] = {0,4,2,6,1,5,3,7};
  float2 d[8];
  dft8<S>(a, d);                                    // stage 0
  #pragma unroll
  for(int k=0;k<8;k++)
    B[SWZR(8*t+k)] = (k==0) ? d[0] : cmul_tw<S>(d[km[k]], tw0[k]);
  lds_fence();
  #pragma unroll
  for(int r=0;r<8;r++) a[r] = B[SWZR(t+64*r)];
  lds_fence();
  dft8<S>(a, d);                                    // stage 1
  {
    int p = t>>3, q = t&7;
    #pragma unroll
    for(int k=0;k<8;k++)
      B[SWZR(q + 64*p + 8*k)] = (k==0) ? d[0] : cmul_tw<S>(d[km[k]], tw1[k]);
  }
  lds_fence();
  #pragma unroll
  for(int r=0;r<8;r++) a[r] = B[SWZR(t+64*r)];
  lds_fence();                                      // data in regs; B reusable
  dft8<S>(a, d);                                    // stage 2
  #pragma unroll
  for(int k=0;k<8;k++) o[k] = make_float2(d[km[k]].x*scale, d[km[k]].y*scale);
}

// 512-pt FFT, block-shared 64KB stage, SIDX16 swizzle (col kernel).
// Caller must barrier before reusing B for writes after this returns.
template<int S>
__device__ __forceinline__ void fft512_c16(float2* a, float2* o, float2* B, int t, int cx,
                                           float scale, const float2* tw0, const float2* tw1){
  const int km[8] = {0,4,2,6,1,5,3,7};
  float2 d[8];
  dft8<S>(a, d);                                    // stage 0
  #pragma unroll
  for(int k=0;k<8;k++)
    B[SIDX16(8*t+k, cx)] = (k==0) ? d[0] : cmul_tw<S>(d[km[k]], tw0[k]);
  __syncthreads();
  #pragma unroll
  for(int r=0;r<8;r++) a[r] = B[SIDX16(t+64*r, cx)];
  __syncthreads();
  dft8<S>(a, d);                                    // stage 1
  {
    int p = t>>3, q = t&7;
    #pragma unroll
    for(int k=0;k<8;k++)
      B[SIDX16(q + 64*p + 8*k, cx)] = (k==0) ? d[0] : cmul_tw<S>(d[km[k]], tw1[k]);
  }
  __syncthreads();
  #pragma unroll
  for(int r=0;r<8;r++) a[r] = B[SIDX16(t+64*r, cx)];
  dft8<S>(a, d);                                    // stage 2, regs only
  #pragma unroll
  for(int k=0;k<8;k++) o[k] = make_float2(d[km[k]].x*scale, d[km[k]].y*scale);
}

// --- Field accessors ---------------------------------------------------------

struct AccH {                            // fp16 interleaved (primary)
  __half2* p;
  __device__ __forceinline__ float2 ld(int i) const { return __half22float2(p[i]); }
  __device__ __forceinline__ void   st(int i, float2 v) const { p[i] = __floats2half2_rn(v.x, v.y); }
};
struct AccS {                            // split f32 planes (fallback)
  float* re; float* im;
  __device__ __forceinline__ float2 ld(int i) const { return make_float2(re[i], im[i]); }
  __device__ __forceinline__ void   st(int i, float2 v) const { re[i]=v.x; im[i]=v.y; }
};

// --- Setup kernel: H1(0.03) and H12 = H(0.03)*H(0.05), f32 ------------------

__device__ __forceinline__ float2 phase_of(float kz, float zf){
  float tt = __fmul_rn(kz, zf);
  double dt = (double)tt;                          // accurate mod-2pi reduction
  double q  = rint(dt * 0.15915494309189535);
  double rr = fma(-q, 6.283185307179586, dt);
  float sn, cs; __sincosf((float)rr, &sn, &cs);
  return make_float2(cs, sn);
}

__global__ __launch_bounds__(256) void k_htab(const float* __restrict__ lams,
                                              float2* __restrict__ H1, float2* __restrict__ H12){
  int e = blockIdx.x*256 + threadIdx.x;            // e < 3*512*512
  int c = e >> 18, fy = (e>>9)&511, col = e&511;
  const float lam = lams[c];
  const float il  = 1.0f / lam;
  const float il2 = __fmul_rn(il, il);
  const float DEN = (float)(512.0 * 8e-6);
  int   sx  = (col < 256) ? col : col - 512;
  int   sy  = (fy  < 256) ? fy  : fy  - 512;
  float fxv = (float)sx / DEN, fyv = (float)sy / DEN;
  float arg = __fsub_rn(il2, __fadd_rn(__fmul_rn(fxv,fxv), __fmul_rn(fyv,fyv)));
  float2 h1 = make_float2(0.0f,0.0f), h12 = h1;
  if(arg > 0.0f){
    float s  = (float)sqrt((double)arg);           // correctly-rounded f32 sqrt
    float kz = __fmul_rn(6.2831854820251465f, s);
    h1  = phase_of(kz, 0.03f);
    h12 = cmul(h1, phase_of(kz, 0.05f));
  }
  H1[e] = h1; H12[e] = h12;
}

// --- Row pass kernels: one wave per row, 4 rows per block, barrier-free ------

template<class Acc>
__global__ __launch_bounds__(256) void k_row_first(
    const float* __restrict__ x, Acc f,
    const float* __restrict__ phases, const float* __restrict__ coeffs)
{
  __shared__ float2 lds[4][512];
  const int w = threadIdx.x >> 6, t = threadIdx.x & 63;
  const int img = blockIdx.x, c = img % 3;
  const int row = (blockIdx.y<<2) + w;
  const int base = (img*512 + row)*512;
  const float* ph = phases + row*512;              // layer 0
  const float coeff = coeffs[c];
  float2 tw0[8], tw1[8]; make_tw(t, tw0, tw1);
  float2 a[8], o[8];
  #pragma unroll
  for(int r=0;r<8;r++){
    int i = t + (r<<6);
    float xv = x[base+i];
    float th = __fmul_rn(ph[i], coeff);
    float sn, cs; __sincosf(th, &sn, &cs);
    a[r] = make_float2(xv*cs, xv*sn);
  }
  fft512_wv<-1>(a, o, lds[w], t, 1.0f, tw0, tw1);
  #pragma unroll
  for(int k=0;k<8;k++){ int i=t+(k<<6); f.st(base+i, o[k]); }
}

template<class Acc>
__global__ __launch_bounds__(256) void k_row_mid(
    Acc f, const float* __restrict__ phases, const float* __restrict__ coeffs, int layer)
{
  __shared__ float2 lds[4][512];
  const int w = threadIdx.x >> 6, t = threadIdx.x & 63;
  const int img = blockIdx.x, c = img % 3;
  const int row = (blockIdx.y<<2) + w;
  const int base = (img*512 + row)*512;
  const float* ph = phases + (layer*512 + row)*512;
  const float coeff = coeffs[layer*3 + c];
  float2 tw0[8], tw1[8]; make_tw(t, tw0, tw1);
  float2 a[8], o[8], pv[8];
  #pragma unroll
  for(int r=0;r<8;r++){
    int i=t+(r<<6); a[r]=f.ld(base+i);
    float th = __fmul_rn(ph[i], coeff);
    float sn, cs; __sincosf(th, &sn, &cs);
    pv[r] = make_float2(cs, sn);
  }
  fft512_wv<+1>(a, o, lds[w], t, 1.0f/512.0f, tw0, tw1);   // row IFFT
  #pragma unroll
  for(int k=0;k<8;k++) a[k] = cmul(o[k], pv[k]);
  fft512_wv<-1>(a, o, lds[w], t, 1.0f, tw0, tw1);          // row FFT
  #pragma unroll
  for(int k=0;k<8;k++){ int i=t+(k<<6); f.st(base+i, o[k]); }
}

template<class Acc>
__global__ __launch_bounds__(256) void k_row_last(
    Acc f, float* __restrict__ out)
{
  __shared__ float2 lds[4][512];
  const int w = threadIdx.x >> 6, t = threadIdx.x & 63;
  const int img = blockIdx.x;
  const int row = (blockIdx.y<<2) + w;
  const int base = (img*512 + row)*512;
  float2 tw0[8], tw1[8]; make_tw(t, tw0, tw1);
  float2 a[8], o[8];
  #pragma unroll
  for(int r=0;r<8;r++){ int i=t+(r<<6); a[r]=f.ld(base+i); }
  fft512_wv<+1>(a, o, lds[w], t, 1.0f/512.0f, tw0, tw1);   // row IFFT
  #pragma unroll
  for(int k=0;k<8;k++){ int i=t+(k<<6); out[base+i] = o[k].x*o[k].x + o[k].y*o[k].y; }
}

// --- Column pass: 1024 thr, 16 cols, one col/thread, 64KB SIDX16 stage -------
// H loaded AFTER the forward FFT (no prefetch array) -> live set <= 48 VGPR.

__global__ __launch_bounds__(1024, 4) void k_col16(
    __half2* __restrict__ F, const float2* __restrict__ Htab)
{
  __shared__ float2 stage[512*16];      // 64 KiB
  const int cx = threadIdx.x & 15, t = threadIdx.x >> 4;
  const int img = blockIdx.x, c = img % 3;
  const int col = (blockIdx.y<<4) + cx;
  const int ibase = (img<<18) + col;
  float2 tw0[8], tw1[8]; make_tw(t, tw0, tw1);
  float2 a[8], o[8];
  #pragma unroll
  for(int r=0;r<8;r++){
    int gi = ibase + ((t+(r<<6))<<9);
    a[r] = __half22float2(F[gi]);
  }
  fft512_c16<-1>(a, o, stage, t, cx, 1.0f, tw0, tw1);          // col FFT
  {
    const float2* Hcol = Htab + (c<<18) + col;     // L2/L3-resident; load late,
    #pragma unroll
    for(int k=0;k<8;k++){                          // consume immediately
      float2 h = Hcol[(t+(k<<6))<<9];
      a[k] = cmul(o[k], h);
    }
  }
  __syncthreads();                                              // stage reuse fence
  fft512_c16<+1>(a, o, stage, t, cx, 1.0f/512.0f, tw0, tw1);   // col IFFT
  #pragma unroll
  for(int k=0;k<8;k++){
    int gi = ibase + ((t+(k<<6))<<9);
    F[gi] = __floats2half2_rn(o[k].x, o[k].y);
  }
}

// --- Fallback column pass (f32 split planes): 8 cols / 512-thr block ---------

__device__ __forceinline__ int CIDX(int e, int cx){
  return ((e ^ ((e>>3)&1))<<3) | (cx ^ ((e>>1)&7));
}

template<int S>
__device__ __forceinline__ void fft512_cs(float2* a, float2* o, float2* B, int t, int cx,
                                          float scale, const float2* tw0, const float2* tw1){
  const int km[8] = {0,4,2,6,1,5,3,7};
  float2 d[8];
  dft8<S>(a, d);
  #pragma unroll
  for(int k=0;k<8;k++)
    B[CIDX(8*t+k, cx)] = (k==0) ? d[0] : cmul_tw<S>(d[km[k]], tw0[k]);
  __syncthreads();
  #pragma unroll
  for(int r=0;r<8;r++) a[r] = B[CIDX(t+64*r, cx)];
  __syncthreads();
  dft8<S>(a, d);
  {
    int p = t>>3, q = t&7;
    #pragma unroll
    for(int k=0;k<8;k++)
      B[CIDX(q + 64*p + 8*k, cx)] = (k==0) ? d[0] : cmul_tw<S>(d[km[k]], tw1[k]);
  }
  __syncthreads();
  #pragma unroll
  for(int r=0;r<8;r++) a[r] = B[CIDX(t+64*r, cx)];
  dft8<S>(a, d);
  #pragma unroll
  for(int k=0;k<8;k++) o[k] = make_float2(d[km[k]].x*scale, d[km[k]].y*scale);
}

template<class Acc, bool TAB>
__global__ __launch_bounds__(512, 4) void k_col8(
    Acc f, const float2* __restrict__ Htab, const float* __restrict__ lams, float z1, float z2)
{
  __shared__ float2 lds[512*8];         // 32 KiB, CIDX swizzled
  const int cx = threadIdx.x & 7, t = threadIdx.x >> 3;
  const int img = blockIdx.x, c = img % 3;
  const int col = (blockIdx.y<<3) + cx;
  const int ibase = (img<<18) + col;
  float2 tw0[8], tw1[8]; make_tw(t, tw0, tw1);
  float2 a[8], o[8], h[8];
  #pragma unroll
  for(int r=0;r<8;r++){ int gi = ibase + ((t+(r<<6))<<9); a[r]=f.ld(gi); }
  if(TAB){
    const float2* Hrow = Htab + (c<<18) + col;
    #pragma unroll
    for(int k=0;k<8;k++) h[k] = Hrow[(t+(k<<6))<<9];
  } else {
    const float lam = lams[c];
    const float il  = 1.0f / lam;
    const float il2 = __fmul_rn(il, il);
    const float DEN = (float)(512.0 * 8e-6);
    int   sx  = (col < 256) ? col : col - 512;
    float fxv = (float)sx / DEN;
    float fx2 = __fmul_rn(fxv, fxv);
    #pragma unroll
    for(int k=0;k<8;k++){
      int fy = t + (k<<6);
      int sy = (fy < 256) ? fy : fy - 512;
      float fyv = (float)sy / DEN;
      float arg = __fsub_rn(il2, __fadd_rn(fx2, __fmul_rn(fyv,fyv)));
      h[k] = make_float2(0.0f, 0.0f);
      if(arg > 0.0f){
        float s  = (float)sqrt((double)arg);
        float kz = __fmul_rn(6.2831854820251465f, s);
        h[k] = phase_of(kz, z1);
        if(z2 != 0.0f) h[k] = cmul(h[k], phase_of(kz, z2));
      }
    }
  }
  fft512_cs<-1>(a, o, lds, t, cx, 1.0f, tw0, tw1);
  #pragma unroll
  for(int k=0;k<8;k++) a[k] = cmul(o[k], h[k]);
  __syncthreads();
  fft512_cs<+1>(a, o, lds, t, cx, 1.0f/512.0f, tw0, tw1);
  #pragma unroll
  for(int k=0;k<8;k++){ int gi = ibase + ((t+(k<<6))<<9); f.st(gi, o[k]); }
}

// ---------------------------------------------------------------------------

extern "C" void kernel_launch(void* const* d_in, const int* in_sizes, int n_in,
                              void* d_out, int out_size, void* d_ws, size_t ws_size,
                              hipStream_t stream)
{
  const float* x      = (const float*)d_in[0];
  const float* phases = (const float*)d_in[1];
  const float* coeffs = (const float*)d_in[2];
  const float* lams   = (const float*)d_in[3];
  float* out = (float*)d_out;

  const size_t fldH = (size_t)NPIX*4;              // fp16 interleaved field: 50.3MB
  const size_t splB = (size_t)NPIX*4;              // split f32 im plane:     50.3MB
  const size_t tabB = (size_t)3*512*512*8;         // one H table (f32):       6.3MB

  dim3 gA(48,128), bA(256);
  dim3 gC(48,32),  bC(1024);                       // 16-col one-col/thread pass
  dim3 gB(48,64),  bB(512);                        // fallback col pass
  dim3 gH(3*512*512/256), bH(256);

  if(ws_size >= fldH + 2*tabB){
    // --- mode H: fp16 interleaved field + f32 H tables, 16-col col pass ---
    AccH f { (__half2*)d_ws };
    float2* H1  = (float2*)((char*)d_ws + fldH);
    float2* H12 = H1 + 3*512*512;
    k_htab<<<gH, bH, 0, stream>>>(lams, H1, H12);
    k_row_first<AccH><<<gA, bA, 0, stream>>>(x, f, phases, coeffs);
    for(int l=1; l<=3; l++){
      k_col16<<<gC, bC, 0, stream>>>((__half2*)d_ws, H1);
      k_row_mid<AccH><<<gA, bA, 0, stream>>>(f, phases, coeffs, l);
    }
    k_col16<<<gC, bC, 0, stream>>>((__half2*)d_ws, H12);
    k_row_last<AccH><<<gA, bA, 0, stream>>>(f, out);
  } else if(ws_size >= splB + 2*tabB){
    // --- mode B: split f32 planes + H tables ---
    AccS f { out, (float*)d_ws };
    float2* H1  = (float2*)((char*)d_ws + splB);
    float2* H12 = H1 + 3*512*512;
    k_htab<<<gH, bH, 0, stream>>>(lams, H1, H12);
    k_row_first<AccS><<<gA, bA, 0, stream>>>(x, f, phases, coeffs);
    for(int l=1; l<=3; l++){
      k_col8<AccS,true><<<gB, bB, 0, stream>>>(f, H1, lams, 0.03f, 0.0f);
      k_row_mid<AccS><<<gA, bA, 0, stream>>>(f, phases, coeffs, l);
    }
    k_col8<AccS,true><<<gB, bB, 0, stream>>>(f, H12, lams, 0.03f, 0.0f);
    k_row_last<AccS><<<gA, bA, 0, stream>>>(f, out);
  } else {
    // --- mode C: split f32 planes, inline H ---
    AccS f { out, (float*)d_ws };
    k_row_first<AccS><<<gA, bA, 0, stream>>>(x, f, phases, coeffs);
    for(int l=1; l<=3; l++){
      k_col8<AccS,false><<<gB, bB, 0, stream>>>(f, nullptr, lams, 0.03f, 0.0f);
      k_row_mid<AccS><<<gA, bA, 0, stream>>>(f, phases, coeffs, l);
    }
    k_col8<AccS,false><<<gB, bB, 0, stream>>>(f, nullptr, lams, 0.03f, 0.05f);
    k_row_last<AccS><<<gA, bA, 0, stream>>>(f, out);
  }
}

// Round 18
// 291.398 us; speedup vs baseline: 1.0337x; 1.0337x over previous
//
#include <hip/hip_runtime.h>
#include <hip/hip_fp16.h>
#include <math.h>

// ---------------------------------------------------------------------------
// Multi-layer diffractive optical model (4 layers, 48 images of 512x512 c64).
//   field = x*exp(i*phase*coeff); 4x [prop(H1); phase]; prop(H1*Hf); |field|^2
// NEW STRUCTURE (r18): NO strided column FFTs. Two fp16 field buffers with
// alternating layouts: N = [img][row][col], T = [img][col][row]. Every pass:
//   contiguous reads -> barrier-free wave-private 512-pt FFT (the row-kernel
//   structure measured at HBM peak) -> transposed write through a 32KB LDS
//   tile (ONE block barrier). The old col pass (block-wide LDS exchange,
//   7 barriers) plateaued at 39-52us across 10 structural variants; rows do
//   the same FFT at ~16us. H multiply runs in the T-domain pass using H's
//   fx<->fy symmetry (bitwise: fadd commutative) -> contiguous H reads.
//   Tile swizzle TI(p,j)=(p<<4)|((j+p)&15): 2 lanes/bank (b32 floor) for
//   FFT-wave writes and coop reads; coop global store = 16 lanes x 4B = 64B
//   segments (no partial-line write amplification, r11 evidence).
// Passes: htab; first(N:x -> phase0,Fx -> T); 3x[ prop(T: Fy,xH,Fy^-1 -> N);
//   mid(N: Fx^-1,phase_l,Fx -> T) ]; prop(T,H12 -> N); last(N: Fx^-1,|.|^2).
// Identical fp op sequence & fp16 store points as r14 -> absmax unchanged.
// ---------------------------------------------------------------------------

#define TWOPI_F 6.2831854820251465f
#define RSQ2    0.70710678f
#define NPIX    (48*512*512)

__device__ __forceinline__ float2 cadd(float2 a, float2 b){ return make_float2(a.x+b.x, a.y+b.y); }
__device__ __forceinline__ float2 csub(float2 a, float2 b){ return make_float2(a.x-b.x, a.y-b.y); }
__device__ __forceinline__ float2 cmul(float2 a, float2 b){ return make_float2(a.x*b.x - a.y*b.y, a.x*b.y + a.y*b.x); }

template<int S> __device__ __forceinline__ float2 mul_i(float2 a){   // * (S*i)
  return (S>0) ? make_float2(-a.y, a.x) : make_float2(a.y, -a.x);
}
template<int S> __device__ __forceinline__ float2 mul_w1(float2 a){  // * (1 + S*i)/sqrt2
  return (S>0) ? make_float2(RSQ2*(a.x-a.y), RSQ2*(a.x+a.y))
               : make_float2(RSQ2*(a.x+a.y), RSQ2*(a.y-a.x));
}
template<int S> __device__ __forceinline__ float2 mul_w3(float2 a){  // * (-1 + S*i)/sqrt2
  return (S>0) ? make_float2(RSQ2*(-a.x-a.y), RSQ2*(a.x-a.y))
               : make_float2(RSQ2*(a.y-a.x), RSQ2*(-a.x-a.y));
}
// tw stored with FORWARD sign (exp(-i theta)); S=+1 uses conjugate.
template<int S> __device__ __forceinline__ float2 cmul_tw(float2 v, float2 w){
  float wy = (S>0) ? -w.y : w.y;
  return make_float2(v.x*w.x - v.y*wy, v.x*wy + v.y*w.x);
}

// 8-point DIF DFT; outputs bit-reversed: A_k = d[km[k]], km = {0,4,2,6,1,5,3,7}
template<int S>
__device__ __forceinline__ void dft8(const float2* a, float2* d){
  float2 b0=cadd(a[0],a[4]), b1=cadd(a[1],a[5]), b2=cadd(a[2],a[6]), b3=cadd(a[3],a[7]);
  float2 b4=csub(a[0],a[4]);
  float2 b5=mul_w1<S>(csub(a[1],a[5]));
  float2 b6=mul_i<S> (csub(a[2],a[6]));
  float2 b7=mul_w3<S>(csub(a[3],a[7]));
  float2 c0=cadd(b0,b2), c2=csub(b0,b2);
  float2 c1=cadd(b1,b3), c3=mul_i<S>(csub(b1,b3));
  float2 c4=cadd(b4,b6), c6=csub(b4,b6);
  float2 c5=cadd(b5,b7), c7=mul_i<S>(csub(b5,b7));
  d[0]=cadd(c0,c1); d[1]=csub(c0,c1);
  d[2]=cadd(c2,c3); d[3]=csub(c2,c3);
  d[4]=cadd(c4,c5); d[5]=csub(c4,c5);
  d[6]=cadd(c6,c7); d[7]=csub(c6,c7);
}

// LDS swizzle for stride-1 wave-private buffers: b64 4-lane/bank-pair floor.
__device__ __forceinline__ int SWZR(int i){ return i ^ ((i>>4)&7); }
// Transpose-tile swizzle: p = spanning index (0..511), j = tile slot (0..15).
// Banks: ((p&1)<<4)|((j+p)&15) -> 2 lanes/bank for both access patterns.
__device__ __forceinline__ int TI(int p, int j){ return (p<<4) | ((j + p) & 15); }

// fp16 pack/unpack
__device__ __forceinline__ unsigned int pkh(float2 v){
  __half2 h = __floats2half2_rn(v.x, v.y);
  return *reinterpret_cast<unsigned int*>(&h);
}
__device__ __forceinline__ float2 upkh(unsigned int u){
  __half2 h; *reinterpret_cast<unsigned int*>(&h) = u;
  return __half22float2(h);
}

// Intra-wave LDS fence.
__device__ __forceinline__ void lds_fence(){ asm volatile("s_waitcnt lgkmcnt(0)" ::: "memory"); }

// Per-thread twiddles (forward sign), computed once per kernel.
__device__ __forceinline__ void make_tw(int t, float2* tw0, float2* tw1){
  float sn, cs;
  __sincosf((TWOPI_F/512.0f)*(float)t, &sn, &cs);
  float2 w0 = make_float2(cs, -sn);
  tw0[0] = make_float2(1.0f, 0.0f);
  #pragma unroll
  for(int k=1;k<8;k++) tw0[k] = cmul(tw0[k-1], w0);
  int p = t>>3;
  __sincosf((TWOPI_F/64.0f)*(float)p, &sn, &cs);
  float2 w1 = make_float2(cs, -sn);
  tw1[0] = make_float2(1.0f, 0.0f);
  #pragma unroll
  for(int k=1;k<8;k++) tw1[k] = cmul(tw1[k-1], w1);
}

// 512-pt FFT, wave-private single buffer, stride-1 + SWZR, NO block barriers.
template<int S>
__device__ __forceinline__ void fft512_wv(float2* a, float2* o, float2* B, int t,
                                          float scale, const float2* tw0, const float2* tw1){
  const int km[8] = {0,4,2,6,1,5,3,7};
  float2 d[8];
  dft8<S>(a, d);                                    // stage 0
  #pragma unroll
  for(int k=0;k<8;k++)
    B[SWZR(8*t+k)] = (k==0) ? d[0] : cmul_tw<S>(d[km[k]], tw0[k]);
  lds_fence();
  #pragma unroll
  for(int r=0;r<8;r++) a[r] = B[SWZR(t+64*r)];
  lds_fence();
  dft8<S>(a, d);                                    // stage 1
  {
    int p = t>>3, q = t&7;
    #pragma unroll
    for(int k=0;k<8;k++)
      B[SWZR(q + 64*p + 8*k)] = (k==0) ? d[0] : cmul_tw<S>(d[km[k]], tw1[k]);
  }
  lds_fence();
  #pragma unroll
  for(int r=0;r<8;r++) a[r] = B[SWZR(t+64*r)];
  lds_fence();                                      // data in regs; B reusable
  dft8<S>(a, d);                                    // stage 2
  #pragma unroll
  for(int k=0;k<8;k++) o[k] = make_float2(d[km[k]].x*scale, d[km[k]].y*scale);
}

// --- Field accessors (fallback paths) ----------------------------------------

struct AccH {                            // fp16 interleaved
  __half2* p;
  __device__ __forceinline__ float2 ld(int i) const { return __half22float2(p[i]); }
  __device__ __forceinline__ void   st(int i, float2 v) const { p[i] = __floats2half2_rn(v.x, v.y); }
};
struct AccS {                            // split f32 planes
  float* re; float* im;
  __device__ __forceinline__ float2 ld(int i) const { return make_float2(re[i], im[i]); }
  __device__ __forceinline__ void   st(int i, float2 v) const { re[i]=v.x; im[i]=v.y; }
};

// --- Setup kernel: H1(0.03) and H12 = H(0.03)*H(0.05), f32 (symmetric fx/fy) -

__device__ __forceinline__ float2 phase_of(float kz, float zf){
  float tt = __fmul_rn(kz, zf);
  double dt = (double)tt;                          // accurate mod-2pi reduction
  double q  = rint(dt * 0.15915494309189535);
  double rr = fma(-q, 6.283185307179586, dt);
  float sn, cs; __sincosf((float)rr, &sn, &cs);
  return make_float2(cs, sn);
}

__global__ __launch_bounds__(256) void k_htab(const float* __restrict__ lams,
                                              float2* __restrict__ H1, float2* __restrict__ H12){
  int e = blockIdx.x*256 + threadIdx.x;            // e < 3*512*512
  int c = e >> 18, fy = (e>>9)&511, col = e&511;
  const float lam = lams[c];
  const float il  = 1.0f / lam;
  const float il2 = __fmul_rn(il, il);
  const float DEN = (float)(512.0 * 8e-6);
  int   sx  = (col < 256) ? col : col - 512;
  int   sy  = (fy  < 256) ? fy  : fy  - 512;
  float fxv = (float)sx / DEN, fyv = (float)sy / DEN;
  float arg = __fsub_rn(il2, __fadd_rn(__fmul_rn(fxv,fxv), __fmul_rn(fyv,fyv)));
  float2 h1 = make_float2(0.0f,0.0f), h12 = h1;
  if(arg > 0.0f){
    float s  = (float)sqrt((double)arg);           // correctly-rounded f32 sqrt
    float kz = __fmul_rn(6.2831854820251465f, s);
    h1  = phase_of(kz, 0.03f);
    h12 = cmul(h1, phase_of(kz, 0.05f));
  }
  H1[e] = h1; H12[e] = h12;
}

// --- Primary pass kernels: contiguous FFT + transposed tile write ------------
// Block: 512 thr = 8 waves; 16 spanning lines (2 per wave, sequential).
// LDS: 8x4KB wave-private FFT buffers + 32KB fp16 transpose tile = 64KB.

// first: N-layout f32 input -> phase0 -> Fx -> T-layout fp16
__global__ __launch_bounds__(512, 2) void k_first(
    const float* __restrict__ x, __half2* __restrict__ FT,
    const float* __restrict__ phases, const float* __restrict__ coeffs)
{
  __shared__ float2 priv[8][512];
  __shared__ unsigned int tile[512*16];
  const int w = threadIdx.x >> 6, t = threadIdx.x & 63;
  const int img = blockIdx.x, c = img % 3;
  const int r0 = blockIdx.y << 4;
  const float coeff = coeffs[c];
  float2 tw0[8], tw1[8]; make_tw(t, tw0, tw1);
  #pragma unroll 1
  for(int cc=0; cc<2; cc++){
    const int j = (w<<1)|cc, row = r0 + j;
    const int base = (img*512 + row)*512;
    const float* ph = phases + row*512;            // layer 0
    float2 a[8], o[8];
    #pragma unroll
    for(int r=0;r<8;r++){
      int i = t + (r<<6);
      float xv = x[base+i];
      float th = __fmul_rn(ph[i], coeff);
      float sn, cs; __sincosf(th, &sn, &cs);
      a[r] = make_float2(xv*cs, xv*sn);
    }
    fft512_wv<-1>(a, o, priv[w], t, 1.0f, tw0, tw1);         // Fx
    #pragma unroll
    for(int k=0;k<8;k++) tile[TI(t+(k<<6), j)] = pkh(o[k]);
  }
  __syncthreads();
  const int cx = threadIdx.x & 15, cr = threadIdx.x >> 4;
  __half2* dst = FT + (img<<18) + r0 + cx;         // T[fx][r0+cx]
  #pragma unroll
  for(int g=0; g<16; g++){
    int p = cr + (g<<5);                           // fx
    *reinterpret_cast<unsigned int*>(dst + (p<<9)) = tile[TI(p, cx)];
  }
}

// prop: T-layout -> Fy -> xH -> Fy^-1 -> N-layout. H read contiguous via symmetry.
__global__ __launch_bounds__(512, 2) void k_prop(
    const __half2* __restrict__ FT, __half2* __restrict__ FN,
    const float2* __restrict__ Htab)
{
  __shared__ float2 priv[8][512];
  __shared__ unsigned int tile[512*16];
  const int w = threadIdx.x >> 6, t = threadIdx.x & 63;
  const int img = blockIdx.x, c = img % 3;
  const int f0 = blockIdx.y << 4;
  float2 tw0[8], tw1[8]; make_tw(t, tw0, tw1);
  #pragma unroll 1
  for(int cc=0; cc<2; cc++){
    const int j = (w<<1)|cc, fx = f0 + j;
    const __half2* src  = FT + (img<<18) + (fx<<9);
    const float2*  Hrow = Htab + (c<<18) + (fx<<9);   // H[fy][fx]=H[fx][fy]
    float2 a[8], o[8];
    #pragma unroll
    for(int r=0;r<8;r++)
      a[r] = upkh(*reinterpret_cast<const unsigned int*>(src + t + (r<<6)));
    fft512_wv<-1>(a, o, priv[w], t, 1.0f, tw0, tw1);          // Fy
    #pragma unroll
    for(int k=0;k<8;k++){
      float2 h = Hrow[t + (k<<6)];
      a[k] = cmul(o[k], h);
    }
    fft512_wv<+1>(a, o, priv[w], t, 1.0f/512.0f, tw0, tw1);   // Fy^-1
    #pragma unroll
    for(int k=0;k<8;k++) tile[TI(t+(k<<6), j)] = pkh(o[k]);
  }
  __syncthreads();
  const int cx = threadIdx.x & 15, cr = threadIdx.x >> 4;
  __half2* dst = FN + (img<<18) + f0 + cx;         // N[row][f0+cx]
  #pragma unroll
  for(int g=0; g<16; g++){
    int p = cr + (g<<5);                           // row
    *reinterpret_cast<unsigned int*>(dst + (p<<9)) = tile[TI(p, cx)];
  }
}

// mid: N-layout -> Fx^-1 -> phase_l -> Fx -> T-layout.
__global__ __launch_bounds__(512, 2) void k_mid(
    const __half2* __restrict__ FN, __half2* __restrict__ FT,
    const float* __restrict__ phases, const float* __restrict__ coeffs, int layer)
{
  __shared__ float2 priv[8][512];
  __shared__ unsigned int tile[512*16];
  const int w = threadIdx.x >> 6, t = threadIdx.x & 63;
  const int img = blockIdx.x, c = img % 3;
  const int r0 = blockIdx.y << 4;
  const float coeff = coeffs[layer*3 + c];
  float2 tw0[8], tw1[8]; make_tw(t, tw0, tw1);
  #pragma unroll 1
  for(int cc=0; cc<2; cc++){
    const int j = (w<<1)|cc, row = r0 + j;
    const __half2* src = FN + (img<<18) + (row<<9);
    const float* ph = phases + (layer*512 + row)*512;
    float2 a[8], o[8];
    #pragma unroll
    for(int r=0;r<8;r++)
      a[r] = upkh(*reinterpret_cast<const unsigned int*>(src + t + (r<<6)));
    fft512_wv<+1>(a, o, priv[w], t, 1.0f/512.0f, tw0, tw1);   // Fx^-1
    #pragma unroll
    for(int k=0;k<8;k++){
      int i = t + (k<<6);
      float th = __fmul_rn(ph[i], coeff);
      float sn, cs; __sincosf(th, &sn, &cs);
      a[k] = cmul(o[k], make_float2(cs, sn));
    }
    fft512_wv<-1>(a, o, priv[w], t, 1.0f, tw0, tw1);          // Fx
    #pragma unroll
    for(int k=0;k<8;k++) tile[TI(t+(k<<6), j)] = pkh(o[k]);
  }
  __syncthreads();
  const int cx = threadIdx.x & 15, cr = threadIdx.x >> 4;
  __half2* dst = FT + (img<<18) + r0 + cx;         // T[fx][r0+cx]
  #pragma unroll
  for(int g=0; g<16; g++){
    int p = cr + (g<<5);                           // fx
    *reinterpret_cast<unsigned int*>(dst + (p<<9)) = tile[TI(p, cx)];
  }
}

// last: N-layout -> Fx^-1 -> |.|^2 -> f32 out. Barrier-free 256-thr kernel.
template<class Acc>
__global__ __launch_bounds__(256) void k_row_last(
    Acc f, float* __restrict__ out)
{
  __shared__ float2 lds[4][512];
  const int w = threadIdx.x >> 6, t = threadIdx.x & 63;
  const int img = blockIdx.x;
  const int row = (blockIdx.y<<2) + w;
  const int base = (img*512 + row)*512;
  float2 tw0[8], tw1[8]; make_tw(t, tw0, tw1);
  float2 a[8], o[8];
  #pragma unroll
  for(int r=0;r<8;r++){ int i=t+(r<<6); a[r]=f.ld(base+i); }
  fft512_wv<+1>(a, o, lds[w], t, 1.0f/512.0f, tw0, tw1);   // row IFFT
  #pragma unroll
  for(int k=0;k<8;k++){ int i=t+(k<<6); out[base+i] = o[k].x*o[k].x + o[k].y*o[k].y; }
}

// --- Fallback path (small ws): r17 structure ---------------------------------

template<class Acc>
__global__ __launch_bounds__(256) void k_row_first(
    const float* __restrict__ x, Acc f,
    const float* __restrict__ phases, const float* __restrict__ coeffs)
{
  __shared__ float2 lds[4][512];
  const int w = threadIdx.x >> 6, t = threadIdx.x & 63;
  const int img = blockIdx.x, c = img % 3;
  const int row = (blockIdx.y<<2) + w;
  const int base = (img*512 + row)*512;
  const float* ph = phases + row*512;
  const float coeff = coeffs[c];
  float2 tw0[8], tw1[8]; make_tw(t, tw0, tw1);
  float2 a[8], o[8];
  #pragma unroll
  for(int r=0;r<8;r++){
    int i = t + (r<<6);
    float xv = x[base+i];
    float th = __fmul_rn(ph[i], coeff);
    float sn, cs; __sincosf(th, &sn, &cs);
    a[r] = make_float2(xv*cs, xv*sn);
  }
  fft512_wv<-1>(a, o, lds[w], t, 1.0f, tw0, tw1);
  #pragma unroll
  for(int k=0;k<8;k++){ int i=t+(k<<6); f.st(base+i, o[k]); }
}

template<class Acc>
__global__ __launch_bounds__(256) void k_row_mid(
    Acc f, const float* __restrict__ phases, const float* __restrict__ coeffs, int layer)
{
  __shared__ float2 lds[4][512];
  const int w = threadIdx.x >> 6, t = threadIdx.x & 63;
  const int img = blockIdx.x, c = img % 3;
  const int row = (blockIdx.y<<2) + w;
  const int base = (img*512 + row)*512;
  const float* ph = phases + (layer*512 + row)*512;
  const float coeff = coeffs[layer*3 + c];
  float2 tw0[8], tw1[8]; make_tw(t, tw0, tw1);
  float2 a[8], o[8], pv[8];
  #pragma unroll
  for(int r=0;r<8;r++){
    int i=t+(r<<6); a[r]=f.ld(base+i);
    float th = __fmul_rn(ph[i], coeff);
    float sn, cs; __sincosf(th, &sn, &cs);
    pv[r] = make_float2(cs, sn);
  }
  fft512_wv<+1>(a, o, lds[w], t, 1.0f/512.0f, tw0, tw1);
  #pragma unroll
  for(int k=0;k<8;k++) a[k] = cmul(o[k], pv[k]);
  fft512_wv<-1>(a, o, lds[w], t, 1.0f, tw0, tw1);
  #pragma unroll
  for(int k=0;k<8;k++){ int i=t+(k<<6); f.st(base+i, o[k]); }
}

__device__ __forceinline__ int CIDX(int e, int cx){
  return ((e ^ ((e>>3)&1))<<3) | (cx ^ ((e>>1)&7));
}

template<int S>
__device__ __forceinline__ void fft512_cs(float2* a, float2* o, float2* B, int t, int cx,
                                          float scale, const float2* tw0, const float2* tw1){
  const int km[8] = {0,4,2,6,1,5,3,7};
  float2 d[8];
  dft8<S>(a, d);
  #pragma unroll
  for(int k=0;k<8;k++)
    B[CIDX(8*t+k, cx)] = (k==0) ? d[0] : cmul_tw<S>(d[km[k]], tw0[k]);
  __syncthreads();
  #pragma unroll
  for(int r=0;r<8;r++) a[r] = B[CIDX(t+64*r, cx)];
  __syncthreads();
  dft8<S>(a, d);
  {
    int p = t>>3, q = t&7;
    #pragma unroll
    for(int k=0;k<8;k++)
      B[CIDX(q + 64*p + 8*k, cx)] = (k==0) ? d[0] : cmul_tw<S>(d[km[k]], tw1[k]);
  }
  __syncthreads();
  #pragma unroll
  for(int r=0;r<8;r++) a[r] = B[CIDX(t+64*r, cx)];
  dft8<S>(a, d);
  #pragma unroll
  for(int k=0;k<8;k++) o[k] = make_float2(d[km[k]].x*scale, d[km[k]].y*scale);
}

template<class Acc, bool TAB>
__global__ __launch_bounds__(512, 4) void k_col8(
    Acc f, const float2* __restrict__ Htab, const float* __restrict__ lams, float z1, float z2)
{
  __shared__ float2 lds[512*8];
  const int cx = threadIdx.x & 7, t = threadIdx.x >> 3;
  const int img = blockIdx.x, c = img % 3;
  const int col = (blockIdx.y<<3) + cx;
  const int ibase = (img<<18) + col;
  float2 tw0[8], tw1[8]; make_tw(t, tw0, tw1);
  float2 a[8], o[8], h[8];
  #pragma unroll
  for(int r=0;r<8;r++){ int gi = ibase + ((t+(r<<6))<<9); a[r]=f.ld(gi); }
  if(TAB){
    const float2* Hrow = Htab + (c<<18) + col;
    #pragma unroll
    for(int k=0;k<8;k++) h[k] = Hrow[(t+(k<<6))<<9];
  } else {
    const float lam = lams[c];
    const float il  = 1.0f / lam;
    const float il2 = __fmul_rn(il, il);
    const float DEN = (float)(512.0 * 8e-6);
    int   sx  = (col < 256) ? col : col - 512;
    float fxv = (float)sx / DEN;
    float fx2 = __fmul_rn(fxv, fxv);
    #pragma unroll
    for(int k=0;k<8;k++){
      int fy = t + (k<<6);
      int sy = (fy < 256) ? fy : fy - 512;
      float fyv = (float)sy / DEN;
      float arg = __fsub_rn(il2, __fadd_rn(fx2, __fmul_rn(fyv,fyv)));
      h[k] = make_float2(0.0f, 0.0f);
      if(arg > 0.0f){
        float s  = (float)sqrt((double)arg);
        float kz = __fmul_rn(6.2831854820251465f, s);
        h[k] = phase_of(kz, z1);
        if(z2 != 0.0f) h[k] = cmul(h[k], phase_of(kz, z2));
      }
    }
  }
  fft512_cs<-1>(a, o, lds, t, cx, 1.0f, tw0, tw1);
  #pragma unroll
  for(int k=0;k<8;k++) a[k] = cmul(o[k], h[k]);
  __syncthreads();
  fft512_cs<+1>(a, o, lds, t, cx, 1.0f/512.0f, tw0, tw1);
  #pragma unroll
  for(int k=0;k<8;k++){ int gi = ibase + ((t+(k<<6))<<9); f.st(gi, o[k]); }
}

// ---------------------------------------------------------------------------

extern "C" void kernel_launch(void* const* d_in, const int* in_sizes, int n_in,
                              void* d_out, int out_size, void* d_ws, size_t ws_size,
                              hipStream_t stream)
{
  const float* x      = (const float*)d_in[0];
  const float* phases = (const float*)d_in[1];
  const float* coeffs = (const float*)d_in[2];
  const float* lams   = (const float*)d_in[3];
  float* out = (float*)d_out;

  const size_t fldH = (size_t)NPIX*4;              // one fp16 field: 50.3MB
  const size_t splB = (size_t)NPIX*4;              // split f32 im plane
  const size_t tabB = (size_t)3*512*512*8;         // one H table (f32): 6.3MB

  dim3 gT(48,32),  bT(512);                        // tile passes
  dim3 gL(48,128), bL(256);                        // last pass
  dim3 gH(3*512*512/256), bH(256);

  if(ws_size >= 2*fldH + 2*tabB){
    // --- primary: transposed ping-pong, all-contiguous FFTs ---
    __half2* fldA = (__half2*)d_ws;                          // T layout
    __half2* fldB = (__half2*)((char*)d_ws + fldH);          // N layout
    float2* H1  = (float2*)((char*)d_ws + 2*fldH);
    float2* H12 = H1 + 3*512*512;
    k_htab<<<gH, bH, 0, stream>>>(lams, H1, H12);
    k_first<<<gT, bT, 0, stream>>>(x, fldA, phases, coeffs);
    for(int l=1; l<=3; l++){
      k_prop<<<gT, bT, 0, stream>>>(fldA, fldB, H1);
      k_mid <<<gT, bT, 0, stream>>>(fldB, fldA, phases, coeffs, l);
    }
    k_prop<<<gT, bT, 0, stream>>>(fldA, fldB, H12);
    k_row_last<AccH><<<gL, bL, 0, stream>>>(AccH{fldB}, out);
  } else if(ws_size >= splB + 2*tabB){
    // --- fallback B: split f32 planes + H tables, r17 col pass ---
    AccS f { out, (float*)d_ws };
    float2* H1  = (float2*)((char*)d_ws + splB);
    float2* H12 = H1 + 3*512*512;
    k_htab<<<gH, bH, 0, stream>>>(lams, H1, H12);
    dim3 gB(48,64), bB(512);
    k_row_first<AccS><<<gL, bL, 0, stream>>>(x, f, phases, coeffs);
    for(int l=1; l<=3; l++){
      k_col8<AccS,true><<<gB, bB, 0, stream>>>(f, H1, lams, 0.03f, 0.0f);
      k_row_mid<AccS><<<gL, bL, 0, stream>>>(f, phases, coeffs, l);
    }
    k_col8<AccS,true><<<gB, bB, 0, stream>>>(f, H12, lams, 0.03f, 0.0f);
    k_row_last<AccS><<<gL, bL, 0, stream>>>(f, out);
  } else {
    // --- fallback C: split planes, inline H ---
    AccS f { out, (float*)d_ws };
    dim3 gB(48,64), bB(512);
    k_row_first<AccS><<<gL, bL, 0, stream>>>(x, f, phases, coeffs);
    for(int l=1; l<=3; l++){
      k_col8<AccS,false><<<gB, bB, 0, stream>>>(f, nullptr, lams, 0.03f, 0.0f);
      k_row_mid<AccS><<<gL, bL, 0, stream>>>(f, phases, coeffs, l);
    }
    k_col8<AccS,false><<<gB, bB, 0, stream>>>(f, nullptr, lams, 0.03f, 0.05f);
    k_row_last<AccS><<<gL, bL, 0, stream>>>(f, out);
  }
}